// Round 10
// baseline (346.736 us; speedup 1.0000x reference)
//
#include <hip/hip_runtime.h>
#include <hip/hip_fp16.h>
#include <math.h>

#define N_NODES 50000
#define N_EDGES 1600000
#define D_INF   128
#define D_HID   64
#define BN_EPS  1e-5f
#define NBINS   391      // fine bins, 128 nodes each (bin = dst >> 7)
#define BINCAP  4608     // per-bin cap (mean 4092, +8 sigma)
#define NBLKA   512      // binA blocks
#define EPBA    3125     // edges per binA block (512 x 3125 = E exactly)
#define GEMM1B  3125     // gemm1 blocks inside k_pre
#define NSTATS  196      // bn_stats blocks (256 rows each)

// ============ fused k_pre: blocks 0..511 binA | 512..3636 gemm1 ============
// binA: LDS counting sort -- histogram, scan, bin-grouped LDS staging, then
// per-bin contiguous burst flush to global (zero scattered stores).
// gemm1 writes SPLIT half-tables ha (cols 0-31) / hb (cols 32-63).
struct SmGemm { float sw[D_INF * D_HID]; float sx[16 * D_INF]; };  // 40 KB
struct SmBin  {
    int hcnt[NBINS];        // pass1 hist -> pass2 cursor
    int lofs[NBINS + 1];    // exclusive scan (local offsets)
    int hbase[NBINS];       // global base per bin
    int sscan[512];         // scan scratch
    unsigned long long stage[EPBA];   // 25 KB bin-grouped staging
};                                     // 31.7 KB
union SmPre { SmGemm g; SmBin a; };

__global__ __launch_bounds__(256) void k_pre(const float* __restrict__ wsc,
                                             const float* __restrict__ wfc,
                                             const int*   __restrict__ ei,
                                             const float* __restrict__ alpha,
                                             int* __restrict__ bin_cur,
                                             unsigned long long* __restrict__ binned,
                                             const float* __restrict__ x,
                                             const float* __restrict__ W,
                                             __half* __restrict__ ha,
                                             __half* __restrict__ hb) {
    __shared__ SmPre sm;
    int t = threadIdx.x;
    if (blockIdx.x < NBLKA) {
        // ---------------- binA: LDS counting sort --------------------------
        int e0 = blockIdx.x * EPBA;
        for (int b = t; b < NBINS; b += 256) sm.a.hcnt[b] = 0;
        __syncthreads();
        for (int i = t; i < EPBA; i += 256)
            atomicAdd(&sm.a.hcnt[ei[N_EDGES + e0 + i] >> 7], 1);
        __syncthreads();
        // inclusive scan of hcnt (512-padded Hillis-Steele, 2 slots/thread)
        sm.a.sscan[t]       = (t < NBINS) ? sm.a.hcnt[t] : 0;
        sm.a.sscan[t + 256] = (t + 256 < NBINS) ? sm.a.hcnt[t + 256] : 0;
        __syncthreads();
        for (int off = 1; off < 512; off <<= 1) {
            int v0 = (t       >= off) ? sm.a.sscan[t - off]       : 0;
            int v1 = (t + 256 >= off) ? sm.a.sscan[t + 256 - off] : 0;
            __syncthreads();
            sm.a.sscan[t]       += v0;
            sm.a.sscan[t + 256] += v1;
            __syncthreads();
        }
        if (t == 0) sm.a.lofs[0] = 0;
        for (int b = t; b < NBINS; b += 256) sm.a.lofs[b + 1] = sm.a.sscan[b];
        __syncthreads();
        for (int b = t; b < NBINS; b += 256) {
            int c = sm.a.lofs[b + 1] - sm.a.lofs[b];
            sm.a.hbase[b] = c ? atomicAdd(&bin_cur[b], c) : 0;
            sm.a.hcnt[b] = 0;   // reuse as pass2 cursor
        }
        __syncthreads();
        float a = 1.0f / (1.0f + expf(-alpha[0]));
        for (int i = t; i < EPBA; i += 256) {
            int e = e0 + i;
            int s = ei[e], d = ei[N_EDGES + e];
            float wm = fmaf(a, wsc[e] - wfc[e], wfc[e]);   // a*wsc+(1-a)*wfc
            int bin = d >> 7;
            int slot = atomicAdd(&sm.a.hcnt[bin], 1);
            sm.a.stage[sm.a.lofs[bin] + slot] =
                ((unsigned long long)__float_as_uint(wm) << 32)
                | (unsigned int)(s | ((d & 127) << 16));
        }
        __syncthreads();
        // flush: per-bin contiguous burst (coalesced across lanes)
        int wave = t >> 6, lane = t & 63;
        for (int b = wave; b < NBINS; b += 4) {
            int s0 = sm.a.lofs[b];
            int n  = sm.a.lofs[b + 1] - s0;
            int gb = sm.a.hbase[b];
            n = min(n, BINCAP - gb);           // cap guard
            unsigned long long* dst = binned + (size_t)b * BINCAP + gb;
            for (int i = lane; i < n; i += 64) dst[i] = sm.a.stage[s0 + i];
        }
    } else {
        // ---------------- gemm1: [N,128]x[128,64] -> fp16 halves -----------
        int row0 = (blockIdx.x - NBLKA) * 16;
#pragma unroll
        for (int j = 0; j < 32; ++j) sm.g.sw[t + j * 256] = W[t + j * 256];
#pragma unroll
        for (int j = 0; j < 8; ++j) {
            int i = t + j * 256;
            int r = i >> 7, k = i & 127;
            sm.g.sx[i] = x[(row0 + r) * D_INF + k];
        }
        __syncthreads();
        int c = t & 63, rg = (t >> 6) * 4;
        float a0 = 0, a1 = 0, a2 = 0, a3 = 0;
#pragma unroll 4
        for (int k = 0; k < D_INF; ++k) {
            float w = sm.g.sw[k * D_HID + c];
            a0 = fmaf(sm.g.sx[(rg + 0) * D_INF + k], w, a0);
            a1 = fmaf(sm.g.sx[(rg + 1) * D_INF + k], w, a1);
            a2 = fmaf(sm.g.sx[(rg + 2) * D_INF + k], w, a2);
            a3 = fmaf(sm.g.sx[(rg + 3) * D_INF + k], w, a3);
        }
        __half* tbl = (c < 32) ? ha : hb;
        int cc = c & 31;
        tbl[(row0 + rg + 0) * 32 + cc] = __float2half_rn(a0);
        tbl[(row0 + rg + 1) * 32 + cc] = __float2half_rn(a1);
        tbl[(row0 + rg + 2) * 32 + cc] = __float2half_rn(a2);
        tbl[(row0 + rg + 3) * 32 + cc] = __float2half_rn(a3);
    }
}

// ====== merged phase B (512 thr): LDS-stage entries once; hist -> dinv,
// row_se; scale h by dinv; fill csr. h' = dinv*h fold, csr stores wm only.
__global__ __launch_bounds__(512) void k_binB(const int* __restrict__ bin_cur,
                                              const unsigned long long* __restrict__ binned,
                                              int2*  __restrict__ row_se,
                                              float* __restrict__ dinv,
                                              __half* __restrict__ ha,
                                              __half* __restrict__ hb,
                                              unsigned int* __restrict__ csr) {
    __shared__ unsigned long long stage[BINCAP];   // 36.9 KB
    __shared__ int   ncnt[128];
    __shared__ float ndeg[128];
    __shared__ int   sscan[128];
    __shared__ float sdinv[128];
    __shared__ int   lb[128];
    int t = threadIdx.x;
    int bin = blockIdx.x;
    if (t < 128) { ncnt[t] = 0; ndeg[t] = 0.0f; }
    int cnt = min(bin_cur[bin], BINCAP);
    const unsigned long long* mybin = binned + (size_t)bin * BINCAP;
    for (int i = t; i < cnt; i += 512) stage[i] = mybin[i];
    __syncthreads();
    for (int i = t; i < cnt; i += 512) {
        unsigned long long ent = stage[i];
        unsigned int lo = (unsigned int)ent;
        int nl = (lo >> 16) & 127;
        float wm = __uint_as_float((unsigned int)(ent >> 32));
        atomicAdd(&ncnt[nl], 1);
        atomicAdd(&ndeg[nl], wm);
    }
    __syncthreads();
    int node0 = bin << 7;
    int nnodes = min(128, N_NODES - node0);
    if (t < 128) {
        float dv = rsqrtf(1.0f + ndeg[t]);   // +1 self loop
        sdinv[t] = dv;
        if (t < nnodes) dinv[node0 + t] = dv;
        sscan[t] = ncnt[t];
    }
    __syncthreads();
    for (int off = 1; off < 128; off <<= 1) {
        int u = (t >= off && t < 128) ? sscan[t - off] : 0;
        __syncthreads();
        if (t < 128) sscan[t] += u;
        __syncthreads();
    }
    if (t < nnodes) {
        int s = bin * BINCAP + sscan[t] - ncnt[t];
        row_se[node0 + t] = make_int2(s, s + ncnt[t]);
        lb[t] = s;
    }
    __syncthreads();
    // scale this bin's h rows by dinv (coalesced, 16 KB)
    int nh = nnodes * 32;
    for (int i = t; i < nh; i += 512) {
        int n = i >> 5, c = i & 31;
        float dv = sdinv[n];
        int idx = (node0 + n) * 32 + c;
        ha[idx] = __float2half_rn(__half2float(ha[idx]) * dv);
        hb[idx] = __float2half_rn(__half2float(hb[idx]) * dv);
    }
    if (t < 128) ncnt[t] = 0;   // reuse as fill cursor
    __syncthreads();
    for (int i = t; i < cnt; i += 512) {
        unsigned long long ent = stage[i];
        unsigned int lo = (unsigned int)ent;
        int nl  = (lo >> 16) & 127;
        int src = lo & 0xFFFFu;
        float wm = __uint_as_float((unsigned int)(ent >> 32));
        int slot = atomicAdd(&ncnt[nl], 1);
        unsigned short wh = __half_as_ushort(__float2half_rn(wm));
        csr[lb[nl] + slot] = (unsigned int)src | ((unsigned int)wh << 16);
    }
}

// == gather (512 thr): XCD-pinned split tables; 16 nodes/block, 32 lanes/node
// out[d] = dd * ( sum_e wm_e * h'[s_e] + h'[d] ) + bias   (h' = dinv*h)
__global__ __launch_bounds__(512) void k_gather(const __half* __restrict__ ha,
                                                const __half* __restrict__ hb,
                                                const unsigned int* __restrict__ csr,
                                                const int2*  __restrict__ row_se,
                                                const float* __restrict__ dinv,
                                                const float* __restrict__ bias,
                                                float* __restrict__ out) {
    int t = threadIdx.x;
    int half = blockIdx.x & 1;
    const __half* __restrict__ h = half ? hb : ha;
    int node = (blockIdx.x >> 1) * 16 + (t >> 5);
    int ln = t & 31;
    int2 se = row_se[node];
    float dd = dinv[node];
    float acc = __half2float(h[node * 32 + ln]);   // self term (pre-scaled)
    for (int b = se.x; b < se.y; b += 32) {
        int c0 = min(32, se.y - b);
        unsigned int my = (ln < c0) ? csr[b + ln] : 0u;
        int j = 0;
        for (; j + 7 < c0; j += 8) {   // 8 outstanding gathers
            unsigned int u0 = __shfl(my, j,     32);
            unsigned int u1 = __shfl(my, j + 1, 32);
            unsigned int u2 = __shfl(my, j + 2, 32);
            unsigned int u3 = __shfl(my, j + 3, 32);
            unsigned int u4 = __shfl(my, j + 4, 32);
            unsigned int u5 = __shfl(my, j + 5, 32);
            unsigned int u6 = __shfl(my, j + 6, 32);
            unsigned int u7 = __shfl(my, j + 7, 32);
            float v0 = __half2float(h[(u0 & 0xFFFFu) * 32 + ln]);
            float v1 = __half2float(h[(u1 & 0xFFFFu) * 32 + ln]);
            float v2 = __half2float(h[(u2 & 0xFFFFu) * 32 + ln]);
            float v3 = __half2float(h[(u3 & 0xFFFFu) * 32 + ln]);
            float v4 = __half2float(h[(u4 & 0xFFFFu) * 32 + ln]);
            float v5 = __half2float(h[(u5 & 0xFFFFu) * 32 + ln]);
            float v6 = __half2float(h[(u6 & 0xFFFFu) * 32 + ln]);
            float v7 = __half2float(h[(u7 & 0xFFFFu) * 32 + ln]);
            acc = fmaf(v0, __half2float(__ushort_as_half((unsigned short)(u0 >> 16))), acc);
            acc = fmaf(v1, __half2float(__ushort_as_half((unsigned short)(u1 >> 16))), acc);
            acc = fmaf(v2, __half2float(__ushort_as_half((unsigned short)(u2 >> 16))), acc);
            acc = fmaf(v3, __half2float(__ushort_as_half((unsigned short)(u3 >> 16))), acc);
            acc = fmaf(v4, __half2float(__ushort_as_half((unsigned short)(u4 >> 16))), acc);
            acc = fmaf(v5, __half2float(__ushort_as_half((unsigned short)(u5 >> 16))), acc);
            acc = fmaf(v6, __half2float(__ushort_as_half((unsigned short)(u6 >> 16))), acc);
            acc = fmaf(v7, __half2float(__ushort_as_half((unsigned short)(u7 >> 16))), acc);
        }
        for (; j < c0; ++j) {
            unsigned int u = __shfl(my, j, 32);
            float v = __half2float(h[(u & 0xFFFFu) * 32 + ln]);
            acc = fmaf(v, __half2float(__ushort_as_half((unsigned short)(u >> 16))), acc);
        }
    }
    out[node * D_HID + half * 32 + ln] = fmaf(acc, dd, bias[half * 32 + ln]);
}

// == GEMM2 fused BN1+ReLU in, dinv-scaled split fp16 out: [N,64]x[64,64] ====
__global__ __launch_bounds__(256) void k_gemm2_bn(const float* __restrict__ hin,
                                                  const float* __restrict__ scale,
                                                  const float* __restrict__ shift,
                                                  const float* __restrict__ W,
                                                  const float* __restrict__ dinv,
                                                  __half* __restrict__ ha,
                                                  __half* __restrict__ hb) {
    __shared__ float sw[D_HID * D_HID];   // 16 KB
    __shared__ float sx[16 * D_HID];      // 4 KB
    int t = threadIdx.x;
    int row0 = blockIdx.x * 16;
#pragma unroll
    for (int j = 0; j < 16; ++j) sw[t + j * 256] = W[t + j * 256];
#pragma unroll
    for (int j = 0; j < 4; ++j) {
        int i = t + j * 256;
        int k = i & 63;
        sx[i] = fmaxf(0.0f, fmaf(hin[row0 * D_HID + i], scale[k], shift[k]));
    }
    __syncthreads();
    int c = t & 63, rg = (t >> 6) * 4;
    float a0 = 0, a1 = 0, a2 = 0, a3 = 0;
#pragma unroll 4
    for (int k = 0; k < D_HID; ++k) {
        float w = sw[k * D_HID + c];
        a0 = fmaf(sx[(rg + 0) * D_HID + k], w, a0);
        a1 = fmaf(sx[(rg + 1) * D_HID + k], w, a1);
        a2 = fmaf(sx[(rg + 2) * D_HID + k], w, a2);
        a3 = fmaf(sx[(rg + 3) * D_HID + k], w, a3);
    }
    __half* tbl = (c < 32) ? ha : hb;
    int cc = c & 31;
    tbl[(row0 + rg + 0) * 32 + cc] = __float2half_rn(a0 * dinv[row0 + rg + 0]);
    tbl[(row0 + rg + 1) * 32 + cc] = __float2half_rn(a1 * dinv[row0 + rg + 1]);
    tbl[(row0 + rg + 2) * 32 + cc] = __float2half_rn(a2 * dinv[row0 + rg + 2]);
    tbl[(row0 + rg + 3) * 32 + cc] = __float2half_rn(a3 * dinv[row0 + rg + 3]);
}

// ======== BN stats: per-block partial col sums/sumsq (no atomics) ==========
__global__ __launch_bounds__(256) void k_bn_stats(const float* __restrict__ h,
                                                  float* __restrict__ part) {
    __shared__ float s1[256], s2[256];
    int t = threadIdx.x;
    int col = t & 63;
    int rend = min(N_NODES, (int)((blockIdx.x + 1) * 256));
    float sum = 0.0f, sq = 0.0f;
    for (int r = blockIdx.x * 256 + (t >> 6); r < rend; r += 4) {
        float v = h[r * D_HID + col];
        sum += v; sq += v * v;
    }
    s1[t] = sum; s2[t] = sq;
    __syncthreads();
    if (t < 64) {
        float a = s1[t] + s1[t + 64] + s1[t + 128] + s1[t + 192];
        float b = s2[t] + s2[t + 64] + s2[t + 128] + s2[t + 192];
        part[blockIdx.x * 128 + t]      = a;
        part[blockIdx.x * 128 + 64 + t] = b;
    }
}

// ================= BN finalize: reduce partials -> scale/shift =============
__global__ void k_bn_finalize(const float* __restrict__ part,
                              const float* __restrict__ gamma,
                              const float* __restrict__ beta,
                              float* __restrict__ scale,
                              float* __restrict__ shift) {
    int j = threadIdx.x;
    if (j >= D_HID) return;
    float sum = 0.0f, sq = 0.0f;
    for (int b = 0; b < NSTATS; ++b) {
        sum += part[b * 128 + j];
        sq  += part[b * 128 + 64 + j];
    }
    const float invn = 1.0f / (float)N_NODES;
    float mean = sum * invn;
    float var  = sq * invn - mean * mean;   // biased, matches jnp.var
    float sc   = gamma[j] / sqrtf(var + BN_EPS);
    scale[j] = sc;
    shift[j] = beta[j] - mean * sc;
}

// =============== BN apply + ReLU (in place, float4 vectorized) =============
__global__ void k_bn_apply_relu(float4* __restrict__ h,
                                const float* __restrict__ scale,
                                const float* __restrict__ shift) {
    int idx = blockIdx.x * blockDim.x + threadIdx.x;
    if (idx >= N_NODES * D_HID / 4) return;
    int j = (idx & 15) * 4;
    float4 v = h[idx];
    v.x = fmaxf(0.0f, fmaf(v.x, scale[j],     shift[j]));
    v.y = fmaxf(0.0f, fmaf(v.y, scale[j + 1], shift[j + 1]));
    v.z = fmaxf(0.0f, fmaf(v.z, scale[j + 2], shift[j + 2]));
    v.w = fmaxf(0.0f, fmaf(v.w, scale[j + 3], shift[j + 3]));
    h[idx] = v;
}

extern "C" void kernel_launch(void* const* d_in, const int* in_sizes, int n_in,
                              void* d_out, int out_size, void* d_ws, size_t ws_size,
                              hipStream_t stream) {
    const float* x     = (const float*)d_in[0];
    const int*   ei_sc = (const int*)  d_in[1];   // [2*E] src then dst
    const float* w_sc  = (const float*)d_in[2];
    const float* w_fc  = (const float*)d_in[4];
    const float* alpha = (const float*)d_in[5];
    const float* W1    = (const float*)d_in[6];
    const float* b1    = (const float*)d_in[7];
    const float* W2    = (const float*)d_in[8];
    const float* b2    = (const float*)d_in[9];
    const float* g1    = (const float*)d_in[10];
    const float* be1   = (const float*)d_in[11];
    const float* g2    = (const float*)d_in[12];
    const float* be2   = (const float*)d_in[13];
    float* out = (float*)d_out;

    // ---- workspace layout (8B-aligned members first): ~42 MB
    unsigned long long* binned = (unsigned long long*)d_ws;        // NBINS*BINCAP u64
    int2*  row_se  = (int2*)(binned + (size_t)NBINS * BINCAP);     // N int2
    int*   bin_cur = (int*)(row_se + N_NODES);                     // NBINS
    float* dinv    = (float*)(bin_cur + NBINS);                    // N
    unsigned int* csr = (unsigned int*)(dinv + N_NODES);           // NBINS*BINCAP
    __half* ha     = (__half*)(csr + (size_t)NBINS * BINCAP);      // N*32 halves
    __half* hb     = ha + (size_t)N_NODES * 32;                    // N*32 halves
    float* agg     = (float*)(hb + (size_t)N_NODES * 32);          // N*64
    float* part    = agg + (size_t)N_NODES * D_HID;                // NSTATS*128
    float* bnss    = part + NSTATS * 128;                          // 128: scale|shift

    const int gV4 = (N_NODES * D_HID / 4 + 255) / 256;             // 3125
    const int gGA = (N_NODES / 16) * 2;                            // 6250
    const int gGM = N_NODES / 16;                                  // 3125

    // ---- fused binA+gemm1, then merged CSR build (+dinv fold into h)
    hipMemsetAsync(bin_cur, 0, NBINS * sizeof(int), stream);
    k_pre <<<NBLKA + GEMM1B, 256, 0, stream>>>(w_sc, w_fc, ei_sc, alpha,
                                               bin_cur, binned, x, W1, ha, hb);
    k_binB<<<NBINS, 512, 0, stream>>>(bin_cur, binned, row_se, dinv, ha, hb, csr);

    // ---- layer 1
    k_gather     <<<gGA, 512, 0, stream>>>(ha, hb, csr, row_se, dinv, b1, agg);
    k_bn_stats   <<<NSTATS, 256, 0, stream>>>(agg, part);
    k_bn_finalize<<<1,   64, 0, stream>>>(part, g1, be1, bnss, bnss + 64);

    // ---- layer 2 (BN1+ReLU fused into GEMM2 input; dinv folded into output)
    k_gemm2_bn   <<<gGM, 256, 0, stream>>>(agg, bnss, bnss + 64, W2, dinv, ha, hb);
    k_gather     <<<gGA, 512, 0, stream>>>(ha, hb, csr, row_se, dinv, b2, out);
    k_bn_stats   <<<NSTATS, 256, 0, stream>>>(out, part);
    k_bn_finalize<<<1,   64, 0, stream>>>(part, g2, be2, bnss, bnss + 64);
    k_bn_apply_relu<<<gV4, 256, 0, stream>>>((float4*)out, bnss, bnss + 64);
}

// Round 11
// 315.771 us; speedup vs baseline: 1.0981x; 1.0981x over previous
//
#include <hip/hip_runtime.h>
#include <hip/hip_fp16.h>
#include <math.h>

#define N_NODES 50000
#define N_EDGES 1600000
#define D_INF   128
#define D_HID   64
#define BN_EPS  1e-5f
#define NBINS   391      // fine bins, 128 nodes each (bin = dst >> 7)
#define BINCAP  4608     // per-bin cap (mean 4092, +8 sigma)
#define EPB     6250     // edges per binA block (256 blocks x 6250 = E)
#define GEMM1B  3125     // gemm1 blocks inside k_pre
#define NPAIR   3125     // gather block-pairs (16 nodes each)

// ============ fused k_pre: blocks 0..255 binA | 256..3380 gemm1 ============
// binA: R9's simple 2-pass shared-hist form -- measured floor ~50us,
// invariant to occupancy/privatization/store-coalescing (R4/R5/R10).
// gemm1 writes SPLIT half-tables ha (cols 0-31) / hb (cols 32-63).
struct SmGemm { float sw[D_INF * D_HID]; float sx[16 * D_INF]; };  // 40 KB
struct SmBin  { int hcnt[NBINS]; int hbase[NBINS]; };              // 3.1 KB
union SmPre { SmGemm g; SmBin a; };

__global__ __launch_bounds__(256) void k_pre(const float* __restrict__ wsc,
                                             const float* __restrict__ wfc,
                                             const int*   __restrict__ ei,
                                             const float* __restrict__ alpha,
                                             int* __restrict__ bin_cur,
                                             unsigned long long* __restrict__ binned,
                                             const float* __restrict__ x,
                                             const float* __restrict__ W,
                                             __half* __restrict__ ha,
                                             __half* __restrict__ hb) {
    __shared__ SmPre sm;
    int t = threadIdx.x;
    if (blockIdx.x < 256) {
        // ---------------- binA: bin edges by dst>>7, staged coalesced ------
        int e0 = blockIdx.x * EPB;
        for (int b = t; b < NBINS; b += 256) sm.a.hcnt[b] = 0;
        __syncthreads();
        for (int i = t; i < EPB; i += 256)
            atomicAdd(&sm.a.hcnt[ei[N_EDGES + e0 + i] >> 7], 1);
        __syncthreads();
        for (int b = t; b < NBINS; b += 256) {
            int c = sm.a.hcnt[b];
            sm.a.hbase[b] = c ? atomicAdd(&bin_cur[b], c) : 0;
            sm.a.hcnt[b] = 0;
        }
        __syncthreads();
        float a = 1.0f / (1.0f + expf(-alpha[0]));
        for (int i = t; i < EPB; i += 256) {
            int e = e0 + i;
            int s = ei[e], d = ei[N_EDGES + e];
            float wm = fmaf(a, wsc[e] - wfc[e], wfc[e]);   // a*wsc+(1-a)*wfc
            int bin = d >> 7;
            int slot = atomicAdd(&sm.a.hcnt[bin], 1);
            int gpos = sm.a.hbase[bin] + slot;
            if (gpos < BINCAP) {
                unsigned long long ent =
                    ((unsigned long long)__float_as_uint(wm) << 32)
                    | (unsigned int)(s | ((d & 127) << 16));
                binned[(size_t)bin * BINCAP + gpos] = ent;
            }
        }
    } else {
        // ---------------- gemm1: [N,128]x[128,64] -> fp16 halves -----------
        int row0 = (blockIdx.x - 256) * 16;
#pragma unroll
        for (int j = 0; j < 32; ++j) sm.g.sw[t + j * 256] = W[t + j * 256];
#pragma unroll
        for (int j = 0; j < 8; ++j) {
            int i = t + j * 256;
            int r = i >> 7, k = i & 127;
            sm.g.sx[i] = x[(row0 + r) * D_INF + k];
        }
        __syncthreads();
        int c = t & 63, rg = (t >> 6) * 4;
        float a0 = 0, a1 = 0, a2 = 0, a3 = 0;
#pragma unroll 4
        for (int k = 0; k < D_INF; ++k) {
            float w = sm.g.sw[k * D_HID + c];
            a0 = fmaf(sm.g.sx[(rg + 0) * D_INF + k], w, a0);
            a1 = fmaf(sm.g.sx[(rg + 1) * D_INF + k], w, a1);
            a2 = fmaf(sm.g.sx[(rg + 2) * D_INF + k], w, a2);
            a3 = fmaf(sm.g.sx[(rg + 3) * D_INF + k], w, a3);
        }
        __half* tbl = (c < 32) ? ha : hb;
        int cc = c & 31;
        tbl[(row0 + rg + 0) * 32 + cc] = __float2half_rn(a0);
        tbl[(row0 + rg + 1) * 32 + cc] = __float2half_rn(a1);
        tbl[(row0 + rg + 2) * 32 + cc] = __float2half_rn(a2);
        tbl[(row0 + rg + 3) * 32 + cc] = __float2half_rn(a3);
    }
}

// ====== merged phase B (512 thr): LDS-stage entries once; hist -> dinv,
// row_se; scale h by dinv; fill csr. h' = dinv*h fold, csr stores wm only.
__global__ __launch_bounds__(512) void k_binB(const int* __restrict__ bin_cur,
                                              const unsigned long long* __restrict__ binned,
                                              int2*  __restrict__ row_se,
                                              float* __restrict__ dinv,
                                              __half* __restrict__ ha,
                                              __half* __restrict__ hb,
                                              unsigned int* __restrict__ csr) {
    __shared__ unsigned long long stage[BINCAP];   // 36.9 KB
    __shared__ int   ncnt[128];
    __shared__ float ndeg[128];
    __shared__ int   sscan[128];
    __shared__ float sdinv[128];
    __shared__ int   lb[128];
    int t = threadIdx.x;
    int bin = blockIdx.x;
    if (t < 128) { ncnt[t] = 0; ndeg[t] = 0.0f; }
    int cnt = min(bin_cur[bin], BINCAP);
    const unsigned long long* mybin = binned + (size_t)bin * BINCAP;
    for (int i = t; i < cnt; i += 512) stage[i] = mybin[i];
    __syncthreads();
    for (int i = t; i < cnt; i += 512) {
        unsigned long long ent = stage[i];
        unsigned int lo = (unsigned int)ent;
        int nl = (lo >> 16) & 127;
        float wm = __uint_as_float((unsigned int)(ent >> 32));
        atomicAdd(&ncnt[nl], 1);
        atomicAdd(&ndeg[nl], wm);
    }
    __syncthreads();
    int node0 = bin << 7;
    int nnodes = min(128, N_NODES - node0);
    if (t < 128) {
        float dv = rsqrtf(1.0f + ndeg[t]);   // +1 self loop
        sdinv[t] = dv;
        if (t < nnodes) dinv[node0 + t] = dv;
        sscan[t] = ncnt[t];
    }
    __syncthreads();
    for (int off = 1; off < 128; off <<= 1) {
        int u = (t >= off && t < 128) ? sscan[t - off] : 0;
        __syncthreads();
        if (t < 128) sscan[t] += u;
        __syncthreads();
    }
    if (t < nnodes) {
        int s = bin * BINCAP + sscan[t] - ncnt[t];
        row_se[node0 + t] = make_int2(s, s + ncnt[t]);
        lb[t] = s;
    }
    __syncthreads();
    // scale this bin's h rows by dinv (coalesced, 16 KB)
    int nh = nnodes * 32;
    for (int i = t; i < nh; i += 512) {
        int n = i >> 5, c = i & 31;
        float dv = sdinv[n];
        int idx = (node0 + n) * 32 + c;
        ha[idx] = __float2half_rn(__half2float(ha[idx]) * dv);
        hb[idx] = __float2half_rn(__half2float(hb[idx]) * dv);
    }
    if (t < 128) ncnt[t] = 0;   // reuse as fill cursor
    __syncthreads();
    for (int i = t; i < cnt; i += 512) {
        unsigned long long ent = stage[i];
        unsigned int lo = (unsigned int)ent;
        int nl  = (lo >> 16) & 127;
        int src = lo & 0xFFFFu;
        float wm = __uint_as_float((unsigned int)(ent >> 32));
        int slot = atomicAdd(&ncnt[nl], 1);
        unsigned short wh = __half_as_ushort(__float2half_rn(wm));
        csr[lb[nl] + slot] = (unsigned int)src | ((unsigned int)wh << 16);
    }
}

// == gather (512 thr): XCD-pinned split tables; 16 nodes/block; fused BN
// partial stats (block-reduced col sums/sumsq -> ps/pq[col][blockPair]).
// out[d] = dd * ( sum_e wm_e * h'[s_e] + h'[d] ) + bias   (h' = dinv*h)
__global__ __launch_bounds__(512) void k_gather(const __half* __restrict__ ha,
                                                const __half* __restrict__ hb,
                                                const unsigned int* __restrict__ csr,
                                                const int2*  __restrict__ row_se,
                                                const float* __restrict__ dinv,
                                                const float* __restrict__ bias,
                                                float* __restrict__ out,
                                                float* __restrict__ ps,
                                                float* __restrict__ pq) {
    __shared__ float s1[512], s2[512];
    int t = threadIdx.x;
    int half = blockIdx.x & 1;
    const __half* __restrict__ h = half ? hb : ha;
    int node = (blockIdx.x >> 1) * 16 + (t >> 5);
    int ln = t & 31;
    int2 se = row_se[node];
    float dd = dinv[node];
    float acc = __half2float(h[node * 32 + ln]);   // self term (pre-scaled)
    for (int b = se.x; b < se.y; b += 32) {
        int c0 = min(32, se.y - b);
        unsigned int my = (ln < c0) ? csr[b + ln] : 0u;
        int j = 0;
        for (; j + 7 < c0; j += 8) {   // 8 outstanding gathers
            unsigned int u0 = __shfl(my, j,     32);
            unsigned int u1 = __shfl(my, j + 1, 32);
            unsigned int u2 = __shfl(my, j + 2, 32);
            unsigned int u3 = __shfl(my, j + 3, 32);
            unsigned int u4 = __shfl(my, j + 4, 32);
            unsigned int u5 = __shfl(my, j + 5, 32);
            unsigned int u6 = __shfl(my, j + 6, 32);
            unsigned int u7 = __shfl(my, j + 7, 32);
            float v0 = __half2float(h[(u0 & 0xFFFFu) * 32 + ln]);
            float v1 = __half2float(h[(u1 & 0xFFFFu) * 32 + ln]);
            float v2 = __half2float(h[(u2 & 0xFFFFu) * 32 + ln]);
            float v3 = __half2float(h[(u3 & 0xFFFFu) * 32 + ln]);
            float v4 = __half2float(h[(u4 & 0xFFFFu) * 32 + ln]);
            float v5 = __half2float(h[(u5 & 0xFFFFu) * 32 + ln]);
            float v6 = __half2float(h[(u6 & 0xFFFFu) * 32 + ln]);
            float v7 = __half2float(h[(u7 & 0xFFFFu) * 32 + ln]);
            acc = fmaf(v0, __half2float(__ushort_as_half((unsigned short)(u0 >> 16))), acc);
            acc = fmaf(v1, __half2float(__ushort_as_half((unsigned short)(u1 >> 16))), acc);
            acc = fmaf(v2, __half2float(__ushort_as_half((unsigned short)(u2 >> 16))), acc);
            acc = fmaf(v3, __half2float(__ushort_as_half((unsigned short)(u3 >> 16))), acc);
            acc = fmaf(v4, __half2float(__ushort_as_half((unsigned short)(u4 >> 16))), acc);
            acc = fmaf(v5, __half2float(__ushort_as_half((unsigned short)(u5 >> 16))), acc);
            acc = fmaf(v6, __half2float(__ushort_as_half((unsigned short)(u6 >> 16))), acc);
            acc = fmaf(v7, __half2float(__ushort_as_half((unsigned short)(u7 >> 16))), acc);
        }
        for (; j < c0; ++j) {
            unsigned int u = __shfl(my, j, 32);
            float v = __half2float(h[(u & 0xFFFFu) * 32 + ln]);
            acc = fmaf(v, __half2float(__ushort_as_half((unsigned short)(u >> 16))), acc);
        }
    }
    float v = fmaf(acc, dd, bias[half * 32 + ln]);
    out[node * D_HID + half * 32 + ln] = v;
    // fused BN partial stats: reduce over the 16 nodes (stride-32 tree)
    s1[t] = v; s2[t] = v * v;
    __syncthreads();
#pragma unroll
    for (int off = 256; off >= 32; off >>= 1) {
        if (t < off) { s1[t] += s1[t + off]; s2[t] += s2[t + off]; }
        __syncthreads();
    }
    if (t < 32) {
        int col = half * 32 + t;
        int bp  = blockIdx.x >> 1;
        ps[col * NPAIR + bp] = s1[t];
        pq[col * NPAIR + bp] = s2[t];
    }
}

// ==== BN finalize: 64 blocks, one column each; reduce NPAIR partials =======
__global__ __launch_bounds__(256) void k_bn_fin(const float* __restrict__ ps,
                                                const float* __restrict__ pq,
                                                const float* __restrict__ gamma,
                                                const float* __restrict__ beta,
                                                float* __restrict__ scale,
                                                float* __restrict__ shift) {
    __shared__ float r1[256], r2[256];
    int j = blockIdx.x;
    int t = threadIdx.x;
    float s = 0.0f, q = 0.0f;
    for (int i = t; i < NPAIR; i += 256) {
        s += ps[j * NPAIR + i];
        q += pq[j * NPAIR + i];
    }
    r1[t] = s; r2[t] = q;
    __syncthreads();
#pragma unroll
    for (int off = 128; off; off >>= 1) {
        if (t < off) { r1[t] += r1[t + off]; r2[t] += r2[t + off]; }
        __syncthreads();
    }
    if (t == 0) {
        const float invn = 1.0f / (float)N_NODES;
        float mean = r1[0] * invn;
        float var  = r2[0] * invn - mean * mean;   // biased, matches jnp.var
        float sc   = gamma[j] / sqrtf(var + BN_EPS);
        scale[j] = sc;
        shift[j] = beta[j] - mean * sc;
    }
}

// == GEMM2 fused BN1+ReLU in, dinv-scaled split fp16 out: [N,64]x[64,64] ====
__global__ __launch_bounds__(256) void k_gemm2_bn(const float* __restrict__ hin,
                                                  const float* __restrict__ scale,
                                                  const float* __restrict__ shift,
                                                  const float* __restrict__ W,
                                                  const float* __restrict__ dinv,
                                                  __half* __restrict__ ha,
                                                  __half* __restrict__ hb) {
    __shared__ float sw[D_HID * D_HID];   // 16 KB
    __shared__ float sx[16 * D_HID];      // 4 KB
    int t = threadIdx.x;
    int row0 = blockIdx.x * 16;
#pragma unroll
    for (int j = 0; j < 16; ++j) sw[t + j * 256] = W[t + j * 256];
#pragma unroll
    for (int j = 0; j < 4; ++j) {
        int i = t + j * 256;
        int k = i & 63;
        sx[i] = fmaxf(0.0f, fmaf(hin[row0 * D_HID + i], scale[k], shift[k]));
    }
    __syncthreads();
    int c = t & 63, rg = (t >> 6) * 4;
    float a0 = 0, a1 = 0, a2 = 0, a3 = 0;
#pragma unroll 4
    for (int k = 0; k < D_HID; ++k) {
        float w = sw[k * D_HID + c];
        a0 = fmaf(sx[(rg + 0) * D_HID + k], w, a0);
        a1 = fmaf(sx[(rg + 1) * D_HID + k], w, a1);
        a2 = fmaf(sx[(rg + 2) * D_HID + k], w, a2);
        a3 = fmaf(sx[(rg + 3) * D_HID + k], w, a3);
    }
    __half* tbl = (c < 32) ? ha : hb;
    int cc = c & 31;
    tbl[(row0 + rg + 0) * 32 + cc] = __float2half_rn(a0 * dinv[row0 + rg + 0]);
    tbl[(row0 + rg + 1) * 32 + cc] = __float2half_rn(a1 * dinv[row0 + rg + 1]);
    tbl[(row0 + rg + 2) * 32 + cc] = __float2half_rn(a2 * dinv[row0 + rg + 2]);
    tbl[(row0 + rg + 3) * 32 + cc] = __float2half_rn(a3 * dinv[row0 + rg + 3]);
}

// =============== BN apply + ReLU (in place, float4 vectorized) =============
__global__ void k_bn_apply_relu(float4* __restrict__ h,
                                const float* __restrict__ scale,
                                const float* __restrict__ shift) {
    int idx = blockIdx.x * blockDim.x + threadIdx.x;
    if (idx >= N_NODES * D_HID / 4) return;
    int j = (idx & 15) * 4;
    float4 v = h[idx];
    v.x = fmaxf(0.0f, fmaf(v.x, scale[j],     shift[j]));
    v.y = fmaxf(0.0f, fmaf(v.y, scale[j + 1], shift[j + 1]));
    v.z = fmaxf(0.0f, fmaf(v.z, scale[j + 2], shift[j + 2]));
    v.w = fmaxf(0.0f, fmaf(v.w, scale[j + 3], shift[j + 3]));
    h[idx] = v;
}

extern "C" void kernel_launch(void* const* d_in, const int* in_sizes, int n_in,
                              void* d_out, int out_size, void* d_ws, size_t ws_size,
                              hipStream_t stream) {
    const float* x     = (const float*)d_in[0];
    const int*   ei_sc = (const int*)  d_in[1];   // [2*E] src then dst
    const float* w_sc  = (const float*)d_in[2];
    const float* w_fc  = (const float*)d_in[4];
    const float* alpha = (const float*)d_in[5];
    const float* W1    = (const float*)d_in[6];
    const float* b1    = (const float*)d_in[7];
    const float* W2    = (const float*)d_in[8];
    const float* b2    = (const float*)d_in[9];
    const float* g1    = (const float*)d_in[10];
    const float* be1   = (const float*)d_in[11];
    const float* g2    = (const float*)d_in[12];
    const float* be2   = (const float*)d_in[13];
    float* out = (float*)d_out;

    // ---- workspace layout (8B-aligned members first): ~44 MB
    unsigned long long* binned = (unsigned long long*)d_ws;        // NBINS*BINCAP u64
    int2*  row_se  = (int2*)(binned + (size_t)NBINS * BINCAP);     // N int2
    int*   bin_cur = (int*)(row_se + N_NODES);                     // NBINS
    float* dinv    = (float*)(bin_cur + NBINS);                    // N
    unsigned int* csr = (unsigned int*)(dinv + N_NODES);           // NBINS*BINCAP
    __half* ha     = (__half*)(csr + (size_t)NBINS * BINCAP);      // N*32 halves
    __half* hb     = ha + (size_t)N_NODES * 32;                    // N*32 halves
    float* agg     = (float*)(hb + (size_t)N_NODES * 32);          // N*64
    float* ps      = agg + (size_t)N_NODES * D_HID;                // 64*NPAIR
    float* pq      = ps + 64 * NPAIR;                              // 64*NPAIR
    float* bnss    = pq + 64 * NPAIR;                              // 128: scale|shift

    const int gV4 = (N_NODES * D_HID / 4 + 255) / 256;             // 3125
    const int gGA = NPAIR * 2;                                     // 6250
    const int gGM = N_NODES / 16;                                  // 3125

    // ---- fused binA+gemm1, then merged CSR build (+dinv fold into h)
    hipMemsetAsync(bin_cur, 0, NBINS * sizeof(int), stream);
    k_pre <<<256 + GEMM1B, 256, 0, stream>>>(w_sc, w_fc, ei_sc, alpha,
                                             bin_cur, binned, x, W1, ha, hb);
    k_binB<<<NBINS, 512, 0, stream>>>(bin_cur, binned, row_se, dinv, ha, hb, csr);

    // ---- layer 1 (BN stats fused into gather epilogue)
    k_gather  <<<gGA, 512, 0, stream>>>(ha, hb, csr, row_se, dinv, b1, agg, ps, pq);
    k_bn_fin  <<<64, 256, 0, stream>>>(ps, pq, g1, be1, bnss, bnss + 64);

    // ---- layer 2 (BN1+ReLU fused into GEMM2 input; dinv folded into output)
    k_gemm2_bn<<<gGM, 256, 0, stream>>>(agg, bnss, bnss + 64, W2, dinv, ha, hb);
    k_gather  <<<gGA, 512, 0, stream>>>(ha, hb, csr, row_se, dinv, b2, out, ps, pq);
    k_bn_fin  <<<64, 256, 0, stream>>>(ps, pq, g2, be2, bnss, bnss + 64);
    k_bn_apply_relu<<<gV4, 256, 0, stream>>>((float4*)out, bnss, bnss + 64);
}